// Round 8
// baseline (87.040 us; speedup 1.0000x reference)
//
#include <hip/hip_runtime.h>
#include <hip/hip_bf16.h>

// LocallyConnected2d: B=16, C=32, O=32, H=W=64, K=3x3, pad=1, stride=1.
// out[b,o,h,w] = sum_{c,k} x[b,c,h+dh,w+dw] * weight[o,c,h,w,k]
//
// R8: R7's linear weight staging (TA fix) + DOUBLE-BUFFERED LDS with counted
// vmcnt. R7 serialized: stage -> full vmcnt(0) drain -> compute each c-iter
// (~900cyc HBM stall x 8 iters, no overlap). Now stage(c+1) issues before
// consuming buf(c); wait is s_waitcnt vmcnt(6) (the 6 newer stage instrs),
// so stage(c+1) flies during compute(c).
//  - OO=2 keeps dbuf LDS at 36.9KB -> 4 blocks/CU (16 waves) per m132 lesson.
//  - x taps from bf16 window prepass XW[b][c][66][64] (3 x 8B loads, no masks).
//  - private per-wave LDS slots -> no barriers anywhere.

#define CIN  32
#define OCH  32
#define HH   64
#define WW   64
#define HW   4096
#define BB   8     // batches per thread (batch-split 2)
#define OO   2     // output channels per thread
#define CC   8     // input channels per block (c-split 4)
#define XWR  66    // padded rows in XW

typedef float f32x4 __attribute__((ext_vector_type(4), aligned(16)));
typedef unsigned int u32x2 __attribute__((ext_vector_type(2), aligned(8)));

typedef const __attribute__((address_space(1))) unsigned int* gptr1_t;
typedef __attribute__((address_space(3))) unsigned int* lptr3_t;

__device__ __forceinline__ void stage16(const void* g, void* l) {
    __builtin_amdgcn_global_load_lds((gptr1_t)(unsigned long long)g,
                                     (lptr3_t)(unsigned int)(unsigned long long)l,
                                     16, 0, 0);
}
__device__ __forceinline__ void stage4(const void* g, void* l) {
    __builtin_amdgcn_global_load_lds((gptr1_t)(unsigned long long)g,
                                     (lptr3_t)(unsigned int)(unsigned long long)l,
                                     4, 0, 0);
}

__device__ __forceinline__ unsigned short f2bf(float f) {
    unsigned u = __float_as_uint(f);
    u += 0x7fffu + ((u >> 16) & 1u);
    return (unsigned short)(u >> 16);
}
__device__ __forceinline__ float bf_lo(unsigned v) { return __uint_as_float(v << 16); }
__device__ __forceinline__ float bf_hi(unsigned v) { return __uint_as_float(v & 0xffff0000u); }

__global__ __launch_bounds__(256)
void zero_out_kernel(float* __restrict__ out, int n4) {
    int i = blockIdx.x * 256 + threadIdx.x;
    if (i < n4) ((f32x4*)out)[i] = (f32x4){0.f, 0.f, 0.f, 0.f};
}

// XW[b][c][66][64] : ushort4{bf16 x[w-1], bf16 x[w], bf16 x[w+1], 0};
// rows 0/65 zero (vertical pad), w edges zero.
__global__ __launch_bounds__(256)
void xwin_kernel(const float* __restrict__ x, u32x2* __restrict__ xw) {
    int tid = blockIdx.x * 256 + threadIdx.x;
    const int total = 16 * CIN * XWR * 64;
    if (tid >= total) return;
    const int w  = tid & 63;
    const int r  = (tid >> 6) % XWR;
    const int bc = tid / (XWR * 64);
    const int h  = r - 1;
    float xl = 0.f, xm = 0.f, xr = 0.f;
    if (h >= 0 && h < HH) {
        const float* row = x + (size_t)bc * HW + (size_t)h * WW;
        xl = (w > 0)      ? row[w - 1] : 0.f;
        xm = row[w];
        xr = (w < WW - 1) ? row[w + 1] : 0.f;
    }
    u32x2 v;
    v.x = (unsigned)f2bf(xl) | ((unsigned)f2bf(xm) << 16);
    v.y = (unsigned)f2bf(xr);
    xw[tid] = v;
}

template<bool XWOK>
__global__ __launch_bounds__(256)
void lc2d_kernel(const float* __restrict__ x, const float* __restrict__ wt,
                 const u32x2* __restrict__ xw, float* __restrict__ out) {
    // [buf][ty][oo*576 floats] : 2*4*1152*4B = 36864 B
    __shared__ float smem[2][4][OO * 576];
    const int w  = threadIdx.x;                 // lane == w
    const int ty = threadIdx.y;
    const int h  = blockIdx.x * 4 + ty;
    const int o0 = blockIdx.y * OO;
    const int bz = blockIdx.z & 1;
    const int cg = blockIdx.z >> 1;
    const int b0 = bz * BB;
    const int c0 = cg * CC;

    // fallback-only edge handling
    const float mt = (h > 0) ? 1.f : 0.f, mb = (h < HH - 1) ? 1.f : 0.f;
    const float ml = (w > 0) ? 1.f : 0.f, mr = (w < WW - 1) ? 1.f : 0.f;
    const int iht = (h > 0) ? h - 1 : 0, ihb = (h < HH - 1) ? h + 1 : HH - 1;
    const int cl = (w > 0) ? w - 1 : 0, cr = (w < WW - 1) ? w + 1 : WW - 1;

    float acc[OO][BB];
#pragma unroll
    for (int oo = 0; oo < OO; ++oo)
#pragma unroll
        for (int b = 0; b < BB; ++b) acc[oo][b] = 0.f;

    // stage one (o,c,h) weight row (2304B contiguous) linearly into LDS
    auto stage_c = [&](int cc, int buf) {
#pragma unroll
        for (int oo = 0; oo < OO; ++oo) {
            const char* src = (const char*)wt
                + ((size_t)(o0 + oo) * CIN + cc) * ((size_t)HW * 36)
                + (size_t)h * 2304;
            float* lb = &smem[buf][ty][oo * 576];
            stage16(src + (size_t)w * 16,        lb);
            stage16(src + 1024 + (size_t)w * 16, lb + 256);
            stage4 (src + 2048 + (size_t)w * 4,  lb + 512);
        }
    };

    stage_c(c0, 0);   // prologue: c=0 into buf 0

    for (int c = 0; c < CC; ++c) {
        const int cur = c & 1;
        // issue next-c stage into the other buffer (last iter: harmless re-stage)
        const int cn = (c + 1 < CC) ? c + 1 : c;
        stage_c(c0 + cn, cur ^ 1);

        // wait for buf[cur]'s 6 stage instrs (the 6 newer ones are cn's)
        asm volatile("s_waitcnt vmcnt(6)" ::: "memory");

        // per-lane weights from LDS (stride-9 dwords; 9 coprime 32 -> 2-way max)
        float wk[OO][9];
#pragma unroll
        for (int oo = 0; oo < OO; ++oo) {
            const float* wp = &smem[cur][ty][oo * 576] + w * 9;
#pragma unroll
            for (int k = 0; k < 9; ++k) wk[oo][k] = wp[k];
        }
        if (!XWOK) {
#pragma unroll
            for (int oo = 0; oo < OO; ++oo) {
                wk[oo][0] *= mt * ml; wk[oo][1] *= mt; wk[oo][2] *= mt * mr;
                wk[oo][3] *= ml;                        wk[oo][5] *= mr;
                wk[oo][6] *= mb * ml; wk[oo][7] *= mb; wk[oo][8] *= mb * mr;
            }
        }

        const int cc = c0 + c;
        size_t xwi = ((size_t)b0 * CIN + cc) * (XWR * 64) + (size_t)h * 64 + w;
#pragma unroll
        for (int b = 0; b < BB; ++b) {
            float t0, t1, t2, t3, t4, t5, t6, t7, t8;
            if (XWOK) {
                const u32x2 r0 = xw[xwi];
                const u32x2 r1 = xw[xwi + 64];
                const u32x2 r2 = xw[xwi + 128];
                t0 = bf_lo(r0.x); t1 = bf_hi(r0.x); t2 = bf_lo(r0.y);
                t3 = bf_lo(r1.x); t4 = bf_hi(r1.x); t5 = bf_lo(r1.y);
                t6 = bf_lo(r2.x); t7 = bf_hi(r2.x); t8 = bf_lo(r2.y);
                xwi += (size_t)CIN * XWR * 64;
            } else {
                const float* xp = x + ((size_t)(b0 + b) * CIN + cc) * HW;
                const float* r0 = xp + iht * WW;
                const float* r1 = xp + h * WW;
                const float* r2 = xp + ihb * WW;
                t0 = r0[cl]; t1 = r0[w]; t2 = r0[cr];
                t3 = r1[cl]; t4 = r1[w]; t5 = r1[cr];
                t6 = r2[cl]; t7 = r2[w]; t8 = r2[cr];
            }
#pragma unroll
            for (int oo = 0; oo < OO; ++oo) {
                float a = acc[oo][b];
                a = fmaf(t0, wk[oo][0], a); a = fmaf(t1, wk[oo][1], a);
                a = fmaf(t2, wk[oo][2], a); a = fmaf(t3, wk[oo][3], a);
                a = fmaf(t4, wk[oo][4], a); a = fmaf(t5, wk[oo][5], a);
                a = fmaf(t6, wk[oo][6], a); a = fmaf(t7, wk[oo][7], a);
                a = fmaf(t8, wk[oo][8], a);
                acc[oo][b] = a;
            }
        }
    }

#pragma unroll
    for (int b = 0; b < BB; ++b)
#pragma unroll
        for (int oo = 0; oo < OO; ++oo)
            atomicAdd(out + (((size_t)(b0 + b) * OCH + (o0 + oo)) * HH + h) * WW + w,
                      acc[oo][b]);
}

extern "C" void kernel_launch(void* const* d_in, const int* in_sizes, int n_in,
                              void* d_out, int out_size, void* d_ws, size_t ws_size,
                              hipStream_t stream) {
    const float* x  = (const float*)d_in[0];
    const float* wt = (const float*)d_in[1];
    float* out = (float*)d_out;

    const int n4 = out_size / 4;
    zero_out_kernel<<<(n4 + 255) / 256, 256, 0, stream>>>(out, n4);

    const size_t ws_need = (size_t)16 * CIN * XWR * 64 * 8;   // 17.3 MB
    dim3 block(64, 4);
    dim3 grid(HH / 4, OCH / OO, 8);   // 16 x 16 x (2 bz * 4 cg) = 2048 blocks

    if (ws_size >= ws_need) {
        u32x2* xw = (u32x2*)d_ws;
        const int total = 16 * CIN * XWR * 64;
        xwin_kernel<<<(total + 255) / 256, 256, 0, stream>>>(x, xw);
        lc2d_kernel<true><<<grid, block, 0, stream>>>(x, wt, xw, out);
    } else {
        lc2d_kernel<false><<<grid, block, 0, stream>>>(x, wt, (const u32x2*)d_ws, out);
    }
}

// Round 9
// 81.335 us; speedup vs baseline: 1.0701x; 1.0701x over previous
//
#include <hip/hip_runtime.h>
#include <hip/hip_bf16.h>

// LocallyConnected2d: B=16, C=32, O=32, H=W=64, K=3x3, pad=1, stride=1.
// out[b,o,h,w] = sum_{c,k} x[b,c,h+dh,w+dw] * weight[o,c,h,w,k]
//
// R9: kill the weight-stream duplication. Since R3, bz=2 batch-split made
// every weight byte flow twice (302MB logical; per-CU HBM share -> ~48us
// floor at pure HBM). Now BB=16 (all batches per thread): weight read ONCE.
//  - OO=4, CC=8, cg=4: grid 512 blocks; 4 atomic addends/output (as R5).
//  - weights: R7's linear global_load_lds staging into private per-wave LDS
//    slots (no barriers), full vmcnt drain per c-iter (simple + correct;
//    R8's counted-vmcnt asm was defeated/serialized by the compiler).
//  - x: bf16 tap-window prepass XW[b][c][66][64] (3 x 8B loads, no masks).

#define CIN  32
#define OCH  32
#define HH   64
#define WW   64
#define HW   4096
#define BB   16    // ALL batches per thread -> weight stream not duplicated
#define OO   4     // output channels per thread
#define CC   8     // input channels per block (c-split 4)
#define XWR  66    // padded rows in XW

typedef float f32x4 __attribute__((ext_vector_type(4), aligned(16)));
typedef unsigned int u32x2 __attribute__((ext_vector_type(2), aligned(8)));

typedef const __attribute__((address_space(1))) unsigned int* gptr1_t;
typedef __attribute__((address_space(3))) unsigned int* lptr3_t;

__device__ __forceinline__ void stage16(const void* g, void* l) {
    __builtin_amdgcn_global_load_lds((gptr1_t)(unsigned long long)g,
                                     (lptr3_t)(unsigned int)(unsigned long long)l,
                                     16, 0, 0);
}
__device__ __forceinline__ void stage4(const void* g, void* l) {
    __builtin_amdgcn_global_load_lds((gptr1_t)(unsigned long long)g,
                                     (lptr3_t)(unsigned int)(unsigned long long)l,
                                     4, 0, 0);
}

__device__ __forceinline__ unsigned short f2bf(float f) {
    unsigned u = __float_as_uint(f);
    u += 0x7fffu + ((u >> 16) & 1u);
    return (unsigned short)(u >> 16);
}
__device__ __forceinline__ float bf_lo(unsigned v) { return __uint_as_float(v << 16); }
__device__ __forceinline__ float bf_hi(unsigned v) { return __uint_as_float(v & 0xffff0000u); }

__global__ __launch_bounds__(256)
void zero_out_kernel(float* __restrict__ out, int n4) {
    int i = blockIdx.x * 256 + threadIdx.x;
    if (i < n4) ((f32x4*)out)[i] = (f32x4){0.f, 0.f, 0.f, 0.f};
}

// XW[b][c][66][64] : ushort4{bf16 x[w-1], bf16 x[w], bf16 x[w+1], 0};
// rows 0/65 zero (vertical pad), w edges zero.
__global__ __launch_bounds__(256)
void xwin_kernel(const float* __restrict__ x, u32x2* __restrict__ xw) {
    int tid = blockIdx.x * 256 + threadIdx.x;
    const int total = 16 * CIN * XWR * 64;
    if (tid >= total) return;
    const int w  = tid & 63;
    const int r  = (tid >> 6) % XWR;
    const int bc = tid / (XWR * 64);
    const int h  = r - 1;
    float xl = 0.f, xm = 0.f, xr = 0.f;
    if (h >= 0 && h < HH) {
        const float* row = x + (size_t)bc * HW + (size_t)h * WW;
        xl = (w > 0)      ? row[w - 1] : 0.f;
        xm = row[w];
        xr = (w < WW - 1) ? row[w + 1] : 0.f;
    }
    u32x2 v;
    v.x = (unsigned)f2bf(xl) | ((unsigned)f2bf(xm) << 16);
    v.y = (unsigned)f2bf(xr);
    xw[tid] = v;
}

template<bool XWOK>
__global__ __launch_bounds__(256)
void lc2d_kernel(const float* __restrict__ x, const float* __restrict__ wt,
                 const u32x2* __restrict__ xw, float* __restrict__ out) {
    // [ty][oo][576 floats] = 4*4*576*4B = 36864 B, single-buffered
    __shared__ float smem[4][OO][576];
    const int w  = threadIdx.x;                 // lane == w
    const int ty = threadIdx.y;
    const int h  = blockIdx.x * 4 + ty;
    const int o0 = blockIdx.y * OO;
    const int cg = blockIdx.z;
    const int c0 = cg * CC;

    // fallback-only edge handling
    const float mt = (h > 0) ? 1.f : 0.f, mb = (h < HH - 1) ? 1.f : 0.f;
    const float ml = (w > 0) ? 1.f : 0.f, mr = (w < WW - 1) ? 1.f : 0.f;
    const int iht = (h > 0) ? h - 1 : 0, ihb = (h < HH - 1) ? h + 1 : HH - 1;
    const int cl = (w > 0) ? w - 1 : 0, cr = (w < WW - 1) ? w + 1 : WW - 1;

    float acc[OO][BB];
#pragma unroll
    for (int oo = 0; oo < OO; ++oo)
#pragma unroll
        for (int b = 0; b < BB; ++b) acc[oo][b] = 0.f;

    for (int c = 0; c < CC; ++c) {
        const int cc = c0 + c;

        // stage 4 weight rows (2304B contiguous each) linearly into LDS
#pragma unroll
        for (int oo = 0; oo < OO; ++oo) {
            const char* src = (const char*)wt
                + ((size_t)(o0 + oo) * CIN + cc) * ((size_t)HW * 36)
                + (size_t)h * 2304;
            float* lb = &smem[ty][oo][0];
            stage16(src + (size_t)w * 16,        lb);
            stage16(src + 1024 + (size_t)w * 16, lb + 256);
            stage4 (src + 2048 + (size_t)w * 4,  lb + 512);
        }
        __builtin_amdgcn_s_waitcnt(0);   // full drain (simple, correct)

        // per-lane weights from LDS (stride-9 dwords: 2-way max = free)
        float wk[OO][9];
#pragma unroll
        for (int oo = 0; oo < OO; ++oo) {
            const float* wp = &smem[ty][oo][0] + w * 9;
#pragma unroll
            for (int k = 0; k < 9; ++k) wk[oo][k] = wp[k];
        }
        if (!XWOK) {
#pragma unroll
            for (int oo = 0; oo < OO; ++oo) {
                wk[oo][0] *= mt * ml; wk[oo][1] *= mt; wk[oo][2] *= mt * mr;
                wk[oo][3] *= ml;                        wk[oo][5] *= mr;
                wk[oo][6] *= mb * ml; wk[oo][7] *= mb; wk[oo][8] *= mb * mr;
            }
        }

        size_t xwi = (size_t)cc * (XWR * 64) + (size_t)h * 64 + w;
#pragma unroll
        for (int b = 0; b < BB; ++b) {
            float t0, t1, t2, t3, t4, t5, t6, t7, t8;
            if (XWOK) {
                const u32x2 r0 = xw[xwi];
                const u32x2 r1 = xw[xwi + 64];
                const u32x2 r2 = xw[xwi + 128];
                t0 = bf_lo(r0.x); t1 = bf_hi(r0.x); t2 = bf_lo(r0.y);
                t3 = bf_lo(r1.x); t4 = bf_hi(r1.x); t5 = bf_lo(r1.y);
                t6 = bf_lo(r2.x); t7 = bf_hi(r2.x); t8 = bf_lo(r2.y);
                xwi += (size_t)CIN * XWR * 64;
            } else {
                const float* xp = x + ((size_t)b * CIN + cc) * HW;
                const float* r0 = xp + iht * WW;
                const float* r1 = xp + h * WW;
                const float* r2 = xp + ihb * WW;
                t0 = r0[cl]; t1 = r0[w]; t2 = r0[cr];
                t3 = r1[cl]; t4 = r1[w]; t5 = r1[cr];
                t6 = r2[cl]; t7 = r2[w]; t8 = r2[cr];
            }
#pragma unroll
            for (int oo = 0; oo < OO; ++oo) {
                float a = acc[oo][b];
                a = fmaf(t0, wk[oo][0], a); a = fmaf(t1, wk[oo][1], a);
                a = fmaf(t2, wk[oo][2], a); a = fmaf(t3, wk[oo][3], a);
                a = fmaf(t4, wk[oo][4], a); a = fmaf(t5, wk[oo][5], a);
                a = fmaf(t6, wk[oo][6], a); a = fmaf(t7, wk[oo][7], a);
                a = fmaf(t8, wk[oo][8], a);
                acc[oo][b] = a;
            }
        }
    }

#pragma unroll
    for (int b = 0; b < BB; ++b)
#pragma unroll
        for (int oo = 0; oo < OO; ++oo)
            atomicAdd(out + (((size_t)b * OCH + (o0 + oo)) * HH + h) * WW + w,
                      acc[oo][b]);
}

extern "C" void kernel_launch(void* const* d_in, const int* in_sizes, int n_in,
                              void* d_out, int out_size, void* d_ws, size_t ws_size,
                              hipStream_t stream) {
    const float* x  = (const float*)d_in[0];
    const float* wt = (const float*)d_in[1];
    float* out = (float*)d_out;

    const int n4 = out_size / 4;
    zero_out_kernel<<<(n4 + 255) / 256, 256, 0, stream>>>(out, n4);

    const size_t ws_need = (size_t)16 * CIN * XWR * 64 * 8;   // 17.3 MB
    dim3 block(64, 4);
    dim3 grid(HH / 4, OCH / OO, 4);   // 16 x 8 x 4 = 512 blocks

    if (ws_size >= ws_need) {
        u32x2* xw = (u32x2*)d_ws;
        const int total = 16 * CIN * XWR * 64;
        xwin_kernel<<<(total + 255) / 256, 256, 0, stream>>>(x, xw);
        lc2d_kernel<true><<<grid, block, 0, stream>>>(x, wt, xw, out);
    } else {
        lc2d_kernel<false><<<grid, block, 0, stream>>>(x, wt, (const u32x2*)d_ws, out);
    }
}